// Round 16
// baseline (201.431 us; speedup 1.0000x reference)
//
#include <hip/hip_runtime.h>
#include <hip/hip_fp16.h>
#include <math.h>
#include <stdint.h>

#define LN_EPS 1e-5f

typedef _Float16 f16x8 __attribute__((ext_vector_type(8)));
typedef _Float16 f16x2 __attribute__((ext_vector_type(2)));
typedef float f32x4 __attribute__((ext_vector_type(4)));

// ---- zero init ----------------------------------------------------------

__global__ void k_zero(int* __restrict__ counts, int N, float* __restrict__ Q, int BQ) {
  int i = blockIdx.x * 256 + threadIdx.x;
  int total = N + BQ;
  for (; i < total; i += gridDim.x * 256) {
    if (i < N) counts[i] = 0;
    else Q[i - N] = 0.f;
  }
}

// ---- CSR build ----------------------------------------------------------

__global__ void k_count(const int* __restrict__ dstA, int E, int NREG,
                        int* __restrict__ counts) {
  int region = blockIdx.x & 7;
  if (region >= NREG) return;
  int e = (blockIdx.x >> 3) * 256 + threadIdx.x;
  if (e < E) {
    int d = dstA[e];
    if ((d >> 13) == region) atomicAdd(&counts[d], 1);
  }
}

__global__ void k_scan1(const int* __restrict__ counts, int N,
                        int* __restrict__ offsets, int* __restrict__ blockSums) {
  __shared__ int sh[256];
  int t = threadIdx.x;
  int i = blockIdx.x * 256 + t;
  int v = (i < N) ? counts[i] : 0;
  sh[t] = v;
  __syncthreads();
  for (int off = 1; off < 256; off <<= 1) {
    int x = (t >= off) ? sh[t - off] : 0;
    __syncthreads();
    sh[t] += x;
    __syncthreads();
  }
  if (i < N) offsets[i] = sh[t] - v;  // exclusive within block
  if (t == 255) blockSums[blockIdx.x] = sh[t];
}

__global__ void k_scan3(int* __restrict__ offsets, int* __restrict__ cursor,
                        const int* __restrict__ blockSums, int N, int E, int NB) {
  __shared__ int sh[256];
  int t = threadIdx.x;
  int bid = blockIdx.x;
  int v = (t < NB && t < bid) ? blockSums[t] : 0;
  sh[t] = v;
  __syncthreads();
  for (int off = 128; off >= 1; off >>= 1) {
    if (t < off) sh[t] += sh[t + off];
    __syncthreads();
  }
  int prefix = sh[0];
  int i = bid * 256 + t;
  if (i < N) {
    int o = offsets[i] + prefix;
    offsets[i] = o;
    cursor[i] = o;
  }
  if (i == 0) offsets[N] = E;
}

// ---- Fused scatter (XCD-partitioned) + proj1 (role-split grid) ----------
// Scatter waves stall on atomic/store latency (VALUBusy ~0.4%); proj1's FMA
// work executes in that shadow. No data dependence between the two roles.
// kv row layout: 16 chunks x 16B, chunk c = [k(4c..4c+3) | v(4c..4c+3)] fp16

__global__ void __launch_bounds__(256) k_scatter_proj1(
    const int* __restrict__ srcA, const int* __restrict__ dstA, int E, int NREG,
    int SB, int* __restrict__ cursor, int* __restrict__ csr_src,
    const float* __restrict__ x, const float* __restrict__ Wk,
    const float* __restrict__ Wv, const float* __restrict__ Wq,
    const float* __restrict__ Wr, int N,
    __half* __restrict__ kvh, __half* __restrict__ qh, float* __restrict__ rb) {
  if ((int)blockIdx.x < SB) {
    int region = blockIdx.x & 7;
    if (region >= NREG) return;
    int e = (blockIdx.x >> 3) * 256 + threadIdx.x;
    if (e < E) {
      int d = dstA[e];
      if ((d >> 13) == region) {
        int pos = atomicAdd(&cursor[d], 1);
        csr_src[pos] = srcA[e];
      }
    }
  } else {
    int t = (blockIdx.x - SB) * 256 + threadIdx.x;
    int n = t >> 6, j = t & 63;
    if (n >= N) return;
    const float* xr = x + (size_t)n * 13;
    float ak = 0.f, av = 0.f, aq = 0.f, ar = 0.f;
#pragma unroll
    for (int i = 0; i < 13; ++i) {
      float xv = xr[i];
      ak = fmaf(xv, Wk[i * 64 + j], ak);
      av = fmaf(xv, Wv[i * 64 + j], av);
      aq = fmaf(xv, Wq[i * 64 + j], aq);
      ar = fmaf(xv, Wr[i * 64 + j], ar);
    }
    __half* row = kvh + (size_t)n * 128;
    int base = (j >> 2) * 8 + (j & 3);
    row[base] = __float2half(ak);
    row[base + 4] = __float2half(av);
    qh[t] = __float2half(aq * 0.25f);
    rb[t] = ar;
  }
}

// MFMA proj2: [N x 64] @ [64 x 64] x3 with fp16 inputs. Small grid (112):
// each wave's B-frag build (192 scalar W loads) is amortized over ~7 tiles.
__global__ void __launch_bounds__(256) k_proj2m(
    const __half* __restrict__ H1h,
    const float* __restrict__ Wk, const float* __restrict__ Wv,
    const float* __restrict__ Wq, int N,
    __half* __restrict__ kvh, __half* __restrict__ qh) {
  int lane = threadIdx.x & 63;
  int wid = threadIdx.x >> 6;
  int col = lane & 15;
  int kgrp = lane >> 4;
  f16x8 bk[2][4], bv[2][4], bq[2][4];  // [k-half][col-tile]
#pragma unroll
  for (int ct = 0; ct < 4; ++ct) {
    int c = ct * 16 + col;
#pragma unroll
    for (int kh = 0; kh < 2; ++kh) {
      int k0 = kh * 32 + kgrp * 8;
      f16x8 fk, fv, fq;
#pragma unroll
      for (int i = 0; i < 8; ++i) {
        fk[i] = (_Float16)Wk[(k0 + i) * 64 + c];
        fv[i] = (_Float16)Wv[(k0 + i) * 64 + c];
        fq[i] = (_Float16)(Wq[(k0 + i) * 64 + c] * 0.25f);  // fold 1/sqrt(dh)
      }
      bk[kh][ct] = fk; bv[kh][ct] = fv; bq[kh][ct] = fq;
    }
  }
  int nTiles = (N + 15) >> 4;
  f32x4 zero = {0.f, 0.f, 0.f, 0.f};
  for (int t = blockIdx.x * 4 + wid; t < nTiles; t += gridDim.x * 4) {
    int n0 = t << 4;
    const f16x8* arow = (const f16x8*)(H1h + ((size_t)n0 + col) * 64);
    f16x8 a0 = arow[kgrp];      // k = 0..31 slice for row n0+col
    f16x8 a1 = arow[4 + kgrp];  // k = 32..63 slice
#pragma unroll
    for (int ct = 0; ct < 4; ++ct) {
      f32x4 ck = __builtin_amdgcn_mfma_f32_16x16x32_f16(a0, bk[0][ct], zero, 0, 0, 0);
      ck = __builtin_amdgcn_mfma_f32_16x16x32_f16(a1, bk[1][ct], ck, 0, 0, 0);
      f32x4 cv = __builtin_amdgcn_mfma_f32_16x16x32_f16(a0, bv[0][ct], zero, 0, 0, 0);
      cv = __builtin_amdgcn_mfma_f32_16x16x32_f16(a1, bv[1][ct], cv, 0, 0, 0);
      f32x4 cq = __builtin_amdgcn_mfma_f32_16x16x32_f16(a0, bq[0][ct], zero, 0, 0, 0);
      cq = __builtin_amdgcn_mfma_f32_16x16x32_f16(a1, bq[1][ct], cq, 0, 0, 0);
#pragma unroll
      for (int r = 0; r < 4; ++r) {
        int node = n0 + kgrp * 4 + r;
        if (node < N) {
          size_t rowo = (size_t)node * 128 + (ct * 4 + (col >> 2)) * 8 + (col & 3);
          kvh[rowo] = __float2half(ck[r]);
          kvh[rowo + 4] = __float2half(cv[r]);
          qh[(size_t)node * 64 + ct * 16 + col] = __float2half(cq[r]);
        }
      }
    }
  }
}

// ---- GAT edge loop: 16 lanes/edge, deg-specialized batching -------------

__device__ __forceinline__ float dot4h(unsigned int k01, unsigned int k23,
                                       unsigned int q01, unsigned int q23) {
#if __has_builtin(__builtin_amdgcn_fdot2)
  float p = __builtin_amdgcn_fdot2(__builtin_bit_cast(f16x2, k01),
                                   __builtin_bit_cast(f16x2, q01), 0.f, false);
  return __builtin_amdgcn_fdot2(__builtin_bit_cast(f16x2, k23),
                                __builtin_bit_cast(f16x2, q23), p, false);
#else
  float2 ka = __half22float2(*(const __half2*)&k01);
  float2 kb = __half22float2(*(const __half2*)&k23);
  float2 qa = __half22float2(*(const __half2*)&q01);
  float2 qb = __half22float2(*(const __half2*)&q23);
  return ka.x * qa.x + ka.y * qa.y + kb.x * qb.x + kb.y * qb.y;
#endif
}

__device__ __forceinline__ void edge_body(uint4 w, bool vf, uint2 qw,
                                          float& denom, float4& acc) {
  float p = dot4h(w.x, w.y, qw.x, qw.y);
  p += __shfl_xor(p, 1, 64);
  p += __shfl_xor(p, 2, 64);  // 16-ch head dot (4-lane subgroup)
  float ex = vf ? __expf(p) : 0.f;
  float2 v01 = __half22float2(*(const __half2*)&w.z);
  float2 v23 = __half22float2(*(const __half2*)&w.w);
  denom += ex;
  acc.x = fmaf(ex, v01.x, acc.x);
  acc.y = fmaf(ex, v01.y, acc.y);
  acc.z = fmaf(ex, v23.x, acc.z);
  acc.w = fmaf(ex, v23.y, acc.w);
}

// batch of NS slots (NS*4 edges), all loads issued before any compute
template <int NS>
__device__ __forceinline__ void edge_batch(const uint4* __restrict__ kvh4,
                                           const int* __restrict__ csr_src,
                                           int e0, int base, int deg,
                                           int grp, int sub, uint2 qw,
                                           float& denom, float4& acc) {
  uint4 w[NS];
  bool vf[NS];
#pragma unroll
  for (int s = 0; s < NS; ++s) {
    int idx = base + s * 4 + grp;
    vf[s] = idx < deg;
    int sv = vf[s] ? csr_src[e0 + idx] : 0;
    w[s] = kvh4[(size_t)sv * 16 + sub];
  }
#pragma unroll
  for (int s = 0; s < NS; ++s) edge_body(w[s], vf[s], qw, denom, acc);
}

__device__ __forceinline__ void edge_loop_h(const uint4* __restrict__ kvh4,
                                            const int* __restrict__ csr_src,
                                            int e0, int deg, int lane, uint2 qw,
                                            float& denom, float4& acc) {
  int grp = lane >> 4;   // edge slot within quad
  int sub = lane & 15;   // 16B channel chunk within row
  // wave-uniform branch (deg identical across the wave)
  if (deg <= 16) {
    edge_batch<4>(kvh4, csr_src, e0, 0, deg, grp, sub, qw, denom, acc);
  } else if (deg <= 32) {
    edge_batch<8>(kvh4, csr_src, e0, 0, deg, grp, sub, qw, denom, acc);
  } else {
    for (int base = 0; base < deg; base += 32)
      edge_batch<8>(kvh4, csr_src, e0, base, deg, grp, sub, qw, denom, acc);
  }
  // combine the 4 edge-slots (lanes l, l+16, l+32, l+48 hold same channels)
#pragma unroll
  for (int off = 16; off <= 32; off <<= 1) {
    acc.x += __shfl_xor(acc.x, off, 64);
    acc.y += __shfl_xor(acc.y, off, 64);
    acc.z += __shfl_xor(acc.z, off, 64);
    acc.w += __shfl_xor(acc.w, off, 64);
    denom += __shfl_xor(denom, off, 64);
  }
}

// LayerNorm; returns normalized 4-ch value for lanes<16 (garbage otherwise)
__device__ __forceinline__ float4 ln_compute(float4 out4, float4 r4,
                                             const float* __restrict__ g,
                                             const float* __restrict__ b, int lane) {
  float4 h;
  h.x = out4.x + r4.x; h.y = out4.y + r4.y; h.z = out4.z + r4.z; h.w = out4.w + r4.w;
  float s = (h.x + h.y) + (h.z + h.w);
#pragma unroll
  for (int off = 1; off <= 8; off <<= 1) s += __shfl_xor(s, off, 64);
  float mu = s * 0.015625f;
  float4 d;
  d.x = h.x - mu; d.y = h.y - mu; d.z = h.z - mu; d.w = h.w - mu;
  float v = (d.x * d.x + d.y * d.y) + (d.z * d.z + d.w * d.w);
#pragma unroll
  for (int off = 1; off <= 8; off <<= 1) v += __shfl_xor(v, off, 64);
  float rs = rsqrtf(v * 0.015625f + LN_EPS);
  float4 o = make_float4(0.f, 0.f, 0.f, 0.f);
  if (lane < 16) {
    int c = lane * 4;
    float4 g4 = *(const float4*)&g[c];
    float4 b4 = *(const float4*)&b[c];
    o.x = fmaf(g4.x, d.x * rs, b4.x);
    o.y = fmaf(g4.y, d.y * rs, b4.y);
    o.z = fmaf(g4.z, d.z * rs, b4.z);
    o.w = fmaf(g4.w, d.w * rs, b4.w);
  }
  return o;
}

// ---- GAT layers ----------------------------------------------------------

__global__ void __launch_bounds__(256) k_gat1(
    const __half* __restrict__ qh, const float* __restrict__ rb,
    const uint4* __restrict__ kvh4,
    const int* __restrict__ offsets, const int* __restrict__ csr_src,
    const float* __restrict__ g, const float* __restrict__ b,
    int N, float* __restrict__ H1, __half* __restrict__ H1h) {
  int wid = threadIdx.x >> 6, lane = threadIdx.x & 63;
  int n = blockIdx.x * 4 + wid;
  if (n >= N) return;
  int sub = lane & 15;
  uint2 qw = *(const uint2*)&qh[(size_t)n * 64 + sub * 4];  // 4 fp16 q ch
  float4 r4 = *(const float4*)&rb[(size_t)n * 64 + sub * 4];
  int e0 = offsets[n];
  int deg = offsets[n + 1] - e0;
  float denom = 0.f;
  float4 acc = make_float4(0.f, 0.f, 0.f, 0.f);
  edge_loop_h(kvh4, csr_src, e0, deg, lane, qw, denom, acc);
  float inv = 1.0f / (denom + 1e-16f);
  float4 out4 = make_float4(acc.x * inv, acc.y * inv, acc.z * inv, acc.w * inv);
  float4 o = ln_compute(out4, r4, g, b, lane);
  if (lane < 16) {
    *(float4*)&H1[(size_t)n * 64 + lane * 4] = o;
    __half2 p0 = __floats2half2_rn(o.x, o.y);
    __half2 p1 = __floats2half2_rn(o.z, o.w);
    uint2 pw;
    pw.x = *(unsigned int*)&p0;
    pw.y = *(unsigned int*)&p1;
    *(uint2*)&H1h[(size_t)n * 64 + lane * 4] = pw;  // fp16 copy for MFMA proj2
  }
}

__global__ void __launch_bounds__(256) k_gat2(
    const float* __restrict__ H1, const __half* __restrict__ qh,
    const uint4* __restrict__ kvh4,
    const int* __restrict__ offsets, const int* __restrict__ csr_src,
    const float* __restrict__ g, const float* __restrict__ b,
    int N, float* __restrict__ H2) {
  int wid = threadIdx.x >> 6, lane = threadIdx.x & 63;
  int n = blockIdx.x * 4 + wid;
  if (n >= N) return;
  int sub = lane & 15;
  uint2 qw = *(const uint2*)&qh[(size_t)n * 64 + sub * 4];
  float4 r4 = *(const float4*)&H1[(size_t)n * 64 + sub * 4];  // identity residual
  int e0 = offsets[n];
  int deg = offsets[n + 1] - e0;
  float denom = 0.f;
  float4 acc = make_float4(0.f, 0.f, 0.f, 0.f);
  edge_loop_h(kvh4, csr_src, e0, deg, lane, qw, denom, acc);
  float inv = 1.0f / (denom + 1e-16f);
  float4 out4 = make_float4(acc.x * inv, acc.y * inv, acc.z * inv, acc.w * inv);
  float4 o = ln_compute(out4, r4, g, b, lane);
  if (lane < 16) *(float4*)&H2[(size_t)n * 64 + lane * 4] = o;
}

// ---- Pooling: B x CHUNKS blocks, LDS reduce, 1 atomic/channel/block -----

#define POOL_CHUNKS 16

__global__ void __launch_bounds__(256) k_pool(const float* __restrict__ H2,
                                              const int* __restrict__ ptr,
                                              float* __restrict__ Q) {
  __shared__ float sh[4 * 64];
  int gI = blockIdx.x / POOL_CHUNKS;
  int c  = blockIdx.x % POOL_CHUNKS;
  int start = ptr[gI], end = ptr[gI + 1];
  int cnt = end - start;
  int per = (cnt + POOL_CHUNKS - 1) / POOL_CHUNKS;
  int s = start + c * per;
  int e = min(s + per, end);
  int wid = threadIdx.x >> 6, lane = threadIdx.x & 63;
  float acc = 0.f;
  for (int n = s + wid; n < e; n += 4) acc += H2[(size_t)n * 64 + lane];
  sh[wid * 64 + lane] = acc;
  __syncthreads();
  if (wid == 0) {
    float v = sh[lane] + sh[64 + lane] + sh[128 + lane] + sh[192 + lane];
    atomicAdd(&Q[(size_t)gI * 64 + lane], v / (float)cnt);
  }
}

// ---- Launch -------------------------------------------------------------

extern "C" void kernel_launch(void* const* d_in, const int* in_sizes, int n_in,
                              void* d_out, int out_size, void* d_ws, size_t ws_size,
                              hipStream_t stream) {
  const float* nodes = (const float*)d_in[0];
  const int* eidx    = (const int*)d_in[1];
  const int* bptr    = (const int*)d_in[2];
  const float* Wq1 = (const float*)d_in[3];
  const float* Wk1 = (const float*)d_in[4];
  const float* Wv1 = (const float*)d_in[5];
  const float* Wr1 = (const float*)d_in[6];
  const float* g1  = (const float*)d_in[7];
  const float* b1  = (const float*)d_in[8];
  const float* Wq2 = (const float*)d_in[9];
  const float* Wk2 = (const float*)d_in[10];
  const float* Wv2 = (const float*)d_in[11];
  const float* g2  = (const float*)d_in[12];
  const float* b2  = (const float*)d_in[13];

  const int N = in_sizes[0] / 13;
  const int E = in_sizes[1] / 2;
  const int B = in_sizes[2] - 1;
  const int* srcA = eidx;
  const int* dstA = eidx + E;

  char* w = (char*)d_ws;
  int* counts    = (int*)w; w += (size_t)N * 4;          // reused as scatter cursor
  int* offsets   = (int*)w; w += (size_t)(N + 1) * 4;
  int* blockSums = (int*)w; w += 256 * 4;
  int* csr_src   = (int*)w; w += (size_t)E * 4;
  w = (char*)(((uintptr_t)w + 255) & ~(uintptr_t)255);
  __half* kvh = (__half*)w; w += (size_t)N * 128 * 2;  // fp16 [k0..3|v0..3] chunks
  __half* qh  = (__half*)w; w += (size_t)N * 64 * 2;   // fp16 q, pre-scaled
  float*  rb  = (float*)w;  w += (size_t)N * 64 * 4;   // fp32 residual (layer 1)
  float*  H1  = (float*)w;  w += (size_t)N * 64 * 4;
  __half* H1h = (__half*)rb;  // rb dead after gat1 -> fp16 H1 for MFMA proj2

  float* H2 = (float*)d_out;
  float* Q  = H2 + (size_t)N * 64;

  const int NB = (N + 255) / 256;
  const int EB = (E + 255) / 256;
  const int GB = (N + 3) / 4;
  const int NREG = ((N - 1) >> 13) + 1;  // 8192-node regions
  const int SB = EB * 8;                 // scatter blocks in fused kernel
  const int PB = (N * 64 + 255) / 256;   // proj1 blocks in fused kernel

  k_zero<<<256, 256, 0, stream>>>(counts, N, Q, B * 64);
  k_count<<<EB * 8, 256, 0, stream>>>(dstA, E, NREG, counts);
  k_scan1<<<NB, 256, 0, stream>>>(counts, N, offsets, blockSums);
  k_scan3<<<NB, 256, 0, stream>>>(offsets, counts, blockSums, N, E, NB);
  k_scatter_proj1<<<SB + PB, 256, 0, stream>>>(srcA, dstA, E, NREG, SB,
                                               counts, csr_src,
                                               nodes, Wk1, Wv1, Wq1, Wr1, N,
                                               kvh, qh, rb);
  k_gat1<<<GB, 256, 0, stream>>>(qh, rb, (const uint4*)kvh, offsets, csr_src,
                                 g1, b1, N, H1, H1h);
  k_proj2m<<<112, 256, 0, stream>>>(H1h, Wk2, Wv2, Wq2, N, kvh, qh);
  k_gat2<<<GB, 256, 0, stream>>>(H1, qh, (const uint4*)kvh, offsets, csr_src,
                                 g2, b2, N, H2);
  k_pool<<<B * POOL_CHUNKS, 256, 0, stream>>>(H2, bptr, Q);
}

// Round 17
// 198.206 us; speedup vs baseline: 1.0163x; 1.0163x over previous
//
#include <hip/hip_runtime.h>
#include <hip/hip_fp16.h>
#include <math.h>
#include <stdint.h>

#define LN_EPS 1e-5f

typedef _Float16 f16x8 __attribute__((ext_vector_type(8)));
typedef _Float16 f16x2 __attribute__((ext_vector_type(2)));
typedef float f32x4 __attribute__((ext_vector_type(4)));

// ---- zero init ----------------------------------------------------------

__global__ void k_zero(int* __restrict__ counts, int N, float* __restrict__ Q, int BQ) {
  int i = blockIdx.x * 256 + threadIdx.x;
  int total = N + BQ;
  for (; i < total; i += gridDim.x * 256) {
    if (i < N) counts[i] = 0;
    else Q[i - N] = 0.f;
  }
}

// ---- CSR build ----------------------------------------------------------

__global__ void k_count(const int* __restrict__ dstA, int E, int NREG,
                        int* __restrict__ counts) {
  int region = blockIdx.x & 7;
  if (region >= NREG) return;
  int e = (blockIdx.x >> 3) * 256 + threadIdx.x;
  if (e < E) {
    int d = dstA[e];
    if ((d >> 13) == region) atomicAdd(&counts[d], 1);
  }
}

__global__ void k_scan1(const int* __restrict__ counts, int N,
                        int* __restrict__ offsets, int* __restrict__ blockSums) {
  __shared__ int sh[256];
  int t = threadIdx.x;
  int i = blockIdx.x * 256 + t;
  int v = (i < N) ? counts[i] : 0;
  sh[t] = v;
  __syncthreads();
  for (int off = 1; off < 256; off <<= 1) {
    int x = (t >= off) ? sh[t - off] : 0;
    __syncthreads();
    sh[t] += x;
    __syncthreads();
  }
  if (i < N) offsets[i] = sh[t] - v;  // exclusive within block
  if (t == 255) blockSums[blockIdx.x] = sh[t];
}

__global__ void k_scan3(int* __restrict__ offsets, int* __restrict__ cursor,
                        const int* __restrict__ blockSums, int N, int E, int NB) {
  __shared__ int sh[256];
  int t = threadIdx.x;
  int bid = blockIdx.x;
  int v = (t < NB && t < bid) ? blockSums[t] : 0;
  sh[t] = v;
  __syncthreads();
  for (int off = 128; off >= 1; off >>= 1) {
    if (t < off) sh[t] += sh[t + off];
    __syncthreads();
  }
  int prefix = sh[0];
  int i = bid * 256 + t;
  if (i < N) {
    int o = offsets[i] + prefix;
    offsets[i] = o;
    cursor[i] = o;
  }
  if (i == 0) offsets[N] = E;
}

__global__ void k_scatter(const int* __restrict__ srcA, const int* __restrict__ dstA,
                          int E, int NREG,
                          int* __restrict__ cursor, int* __restrict__ csr_src) {
  int region = blockIdx.x & 7;
  if (region >= NREG) return;
  int e = (blockIdx.x >> 3) * 256 + threadIdx.x;
  if (e < E) {
    int d = dstA[e];
    if ((d >> 13) == region) {
      int pos = atomicAdd(&cursor[d], 1);
      csr_src[pos] = srcA[e];
    }
  }
}

// ---- Projections --------------------------------------------------------
// kv row layout: 16 chunks x 16B, chunk c = [k(4c..4c+3) | v(4c..4c+3)] fp16

__global__ void k_proj1(const float* __restrict__ x, const float* __restrict__ Wk,
                        const float* __restrict__ Wv, const float* __restrict__ Wq,
                        const float* __restrict__ Wr, int N,
                        __half* __restrict__ kvh, __half* __restrict__ qh,
                        float* __restrict__ rb) {
  int t = blockIdx.x * blockDim.x + threadIdx.x;
  int n = t >> 6, j = t & 63;
  if (n >= N) return;
  const float* xr = x + (size_t)n * 13;
  float ak = 0.f, av = 0.f, aq = 0.f, ar = 0.f;
#pragma unroll
  for (int i = 0; i < 13; ++i) {
    float xv = xr[i];
    ak = fmaf(xv, Wk[i * 64 + j], ak);
    av = fmaf(xv, Wv[i * 64 + j], av);
    aq = fmaf(xv, Wq[i * 64 + j], aq);
    ar = fmaf(xv, Wr[i * 64 + j], ar);
  }
  __half* row = kvh + (size_t)n * 128;
  int base = (j >> 2) * 8 + (j & 3);
  row[base] = __float2half(ak);
  row[base + 4] = __float2half(av);
  qh[t] = __float2half(aq * 0.25f);
  rb[t] = ar;
}

// MFMA proj2: [N x 64] @ [64 x 64] x3 with fp16 inputs.
__global__ void __launch_bounds__(256) k_proj2m(
    const __half* __restrict__ H1h,
    const float* __restrict__ Wk, const float* __restrict__ Wv,
    const float* __restrict__ Wq, int N,
    __half* __restrict__ kvh, __half* __restrict__ qh) {
  int lane = threadIdx.x & 63;
  int wid = threadIdx.x >> 6;
  int col = lane & 15;
  int kgrp = lane >> 4;
  f16x8 bk[2][4], bv[2][4], bq[2][4];  // [k-half][col-tile]
#pragma unroll
  for (int ct = 0; ct < 4; ++ct) {
    int c = ct * 16 + col;
#pragma unroll
    for (int kh = 0; kh < 2; ++kh) {
      int k0 = kh * 32 + kgrp * 8;
      f16x8 fk, fv, fq;
#pragma unroll
      for (int i = 0; i < 8; ++i) {
        fk[i] = (_Float16)Wk[(k0 + i) * 64 + c];
        fv[i] = (_Float16)Wv[(k0 + i) * 64 + c];
        fq[i] = (_Float16)(Wq[(k0 + i) * 64 + c] * 0.25f);  // fold 1/sqrt(dh)
      }
      bk[kh][ct] = fk; bv[kh][ct] = fv; bq[kh][ct] = fq;
    }
  }
  int nTiles = (N + 15) >> 4;
  f32x4 zero = {0.f, 0.f, 0.f, 0.f};
  for (int t = blockIdx.x * 4 + wid; t < nTiles; t += gridDim.x * 4) {
    int n0 = t << 4;
    const f16x8* arow = (const f16x8*)(H1h + ((size_t)n0 + col) * 64);
    f16x8 a0 = arow[kgrp];      // k = 0..31 slice for row n0+col
    f16x8 a1 = arow[4 + kgrp];  // k = 32..63 slice
#pragma unroll
    for (int ct = 0; ct < 4; ++ct) {
      f32x4 ck = __builtin_amdgcn_mfma_f32_16x16x32_f16(a0, bk[0][ct], zero, 0, 0, 0);
      ck = __builtin_amdgcn_mfma_f32_16x16x32_f16(a1, bk[1][ct], ck, 0, 0, 0);
      f32x4 cv = __builtin_amdgcn_mfma_f32_16x16x32_f16(a0, bv[0][ct], zero, 0, 0, 0);
      cv = __builtin_amdgcn_mfma_f32_16x16x32_f16(a1, bv[1][ct], cv, 0, 0, 0);
      f32x4 cq = __builtin_amdgcn_mfma_f32_16x16x32_f16(a0, bq[0][ct], zero, 0, 0, 0);
      cq = __builtin_amdgcn_mfma_f32_16x16x32_f16(a1, bq[1][ct], cq, 0, 0, 0);
#pragma unroll
      for (int r = 0; r < 4; ++r) {
        int node = n0 + kgrp * 4 + r;
        if (node < N) {
          size_t rowo = (size_t)node * 128 + (ct * 4 + (col >> 2)) * 8 + (col & 3);
          kvh[rowo] = __float2half(ck[r]);
          kvh[rowo + 4] = __float2half(cv[r]);
          qh[(size_t)node * 64 + ct * 16 + col] = __float2half(cq[r]);
        }
      }
    }
  }
}

// ---- GAT edge loop: 16 lanes/edge, deg-specialized batching -------------

__device__ __forceinline__ float dot4h(unsigned int k01, unsigned int k23,
                                       unsigned int q01, unsigned int q23) {
#if __has_builtin(__builtin_amdgcn_fdot2)
  float p = __builtin_amdgcn_fdot2(__builtin_bit_cast(f16x2, k01),
                                   __builtin_bit_cast(f16x2, q01), 0.f, false);
  return __builtin_amdgcn_fdot2(__builtin_bit_cast(f16x2, k23),
                                __builtin_bit_cast(f16x2, q23), p, false);
#else
  float2 ka = __half22float2(*(const __half2*)&k01);
  float2 kb = __half22float2(*(const __half2*)&k23);
  float2 qa = __half22float2(*(const __half2*)&q01);
  float2 qb = __half22float2(*(const __half2*)&q23);
  return ka.x * qa.x + ka.y * qa.y + kb.x * qb.x + kb.y * qb.y;
#endif
}

__device__ __forceinline__ void edge_body(uint4 w, bool vf, uint2 qw,
                                          float& denom, float4& acc) {
  float p = dot4h(w.x, w.y, qw.x, qw.y);
  p += __shfl_xor(p, 1, 64);
  p += __shfl_xor(p, 2, 64);  // 16-ch head dot (4-lane subgroup)
  float ex = vf ? __expf(p) : 0.f;
  float2 v01 = __half22float2(*(const __half2*)&w.z);
  float2 v23 = __half22float2(*(const __half2*)&w.w);
  denom += ex;
  acc.x = fmaf(ex, v01.x, acc.x);
  acc.y = fmaf(ex, v01.y, acc.y);
  acc.z = fmaf(ex, v23.x, acc.z);
  acc.w = fmaf(ex, v23.y, acc.w);
}

// batch of NS slots (NS*4 edges), all loads issued before any compute
template <int NS>
__device__ __forceinline__ void edge_batch(const uint4* __restrict__ kvh4,
                                           const int* __restrict__ csr_src,
                                           int e0, int base, int deg,
                                           int grp, int sub, uint2 qw,
                                           float& denom, float4& acc) {
  uint4 w[NS];
  bool vf[NS];
#pragma unroll
  for (int s = 0; s < NS; ++s) {
    int idx = base + s * 4 + grp;
    vf[s] = idx < deg;
    int sv = vf[s] ? csr_src[e0 + idx] : 0;
    w[s] = kvh4[(size_t)sv * 16 + sub];
  }
#pragma unroll
  for (int s = 0; s < NS; ++s) edge_body(w[s], vf[s], qw, denom, acc);
}

__device__ __forceinline__ void edge_loop_h(const uint4* __restrict__ kvh4,
                                            const int* __restrict__ csr_src,
                                            int e0, int deg, int lane, uint2 qw,
                                            float& denom, float4& acc) {
  int grp = lane >> 4;   // edge slot within quad
  int sub = lane & 15;   // 16B channel chunk within row
  // wave-uniform branch (deg identical across the wave)
  if (deg <= 16) {
    edge_batch<4>(kvh4, csr_src, e0, 0, deg, grp, sub, qw, denom, acc);
  } else if (deg <= 32) {
    edge_batch<8>(kvh4, csr_src, e0, 0, deg, grp, sub, qw, denom, acc);
  } else {
    for (int base = 0; base < deg; base += 32)
      edge_batch<8>(kvh4, csr_src, e0, base, deg, grp, sub, qw, denom, acc);
  }
  // combine the 4 edge-slots (lanes l, l+16, l+32, l+48 hold same channels)
#pragma unroll
  for (int off = 16; off <= 32; off <<= 1) {
    acc.x += __shfl_xor(acc.x, off, 64);
    acc.y += __shfl_xor(acc.y, off, 64);
    acc.z += __shfl_xor(acc.z, off, 64);
    acc.w += __shfl_xor(acc.w, off, 64);
    denom += __shfl_xor(denom, off, 64);
  }
}

// LayerNorm; returns normalized 4-ch value for lanes<16 (garbage otherwise)
__device__ __forceinline__ float4 ln_compute(float4 out4, float4 r4,
                                             const float* __restrict__ g,
                                             const float* __restrict__ b, int lane) {
  float4 h;
  h.x = out4.x + r4.x; h.y = out4.y + r4.y; h.z = out4.z + r4.z; h.w = out4.w + r4.w;
  float s = (h.x + h.y) + (h.z + h.w);
#pragma unroll
  for (int off = 1; off <= 8; off <<= 1) s += __shfl_xor(s, off, 64);
  float mu = s * 0.015625f;
  float4 d;
  d.x = h.x - mu; d.y = h.y - mu; d.z = h.z - mu; d.w = h.w - mu;
  float v = (d.x * d.x + d.y * d.y) + (d.z * d.z + d.w * d.w);
#pragma unroll
  for (int off = 1; off <= 8; off <<= 1) v += __shfl_xor(v, off, 64);
  float rs = rsqrtf(v * 0.015625f + LN_EPS);
  float4 o = make_float4(0.f, 0.f, 0.f, 0.f);
  if (lane < 16) {
    int c = lane * 4;
    float4 g4 = *(const float4*)&g[c];
    float4 b4 = *(const float4*)&b[c];
    o.x = fmaf(g4.x, d.x * rs, b4.x);
    o.y = fmaf(g4.y, d.y * rs, b4.y);
    o.z = fmaf(g4.z, d.z * rs, b4.z);
    o.w = fmaf(g4.w, d.w * rs, b4.w);
  }
  return o;
}

// ---- GAT layers ----------------------------------------------------------

// writes H1 in fp16 only (H1h) — consumed by proj2m (A-operand) and gat2
// (residual). fp32 H1 eliminated.
__global__ void __launch_bounds__(256) k_gat1(
    const __half* __restrict__ qh, const float* __restrict__ rb,
    const uint4* __restrict__ kvh4,
    const int* __restrict__ offsets, const int* __restrict__ csr_src,
    const float* __restrict__ g, const float* __restrict__ b,
    int N, __half* __restrict__ H1h) {
  int wid = threadIdx.x >> 6, lane = threadIdx.x & 63;
  int n = blockIdx.x * 4 + wid;
  if (n >= N) return;
  int sub = lane & 15;
  uint2 qw = *(const uint2*)&qh[(size_t)n * 64 + sub * 4];  // 4 fp16 q ch
  float4 r4 = *(const float4*)&rb[(size_t)n * 64 + sub * 4];
  int e0 = offsets[n];
  int deg = offsets[n + 1] - e0;
  float denom = 0.f;
  float4 acc = make_float4(0.f, 0.f, 0.f, 0.f);
  edge_loop_h(kvh4, csr_src, e0, deg, lane, qw, denom, acc);
  float inv = 1.0f / (denom + 1e-16f);
  float4 out4 = make_float4(acc.x * inv, acc.y * inv, acc.z * inv, acc.w * inv);
  float4 o = ln_compute(out4, r4, g, b, lane);
  if (lane < 16) {
    __half2 p0 = __floats2half2_rn(o.x, o.y);
    __half2 p1 = __floats2half2_rn(o.z, o.w);
    uint2 pw;
    pw.x = *(unsigned int*)&p0;
    pw.y = *(unsigned int*)&p1;
    *(uint2*)&H1h[(size_t)n * 64 + lane * 4] = pw;
  }
}

__global__ void __launch_bounds__(256) k_gat2(
    const __half* __restrict__ H1h, const __half* __restrict__ qh,
    const uint4* __restrict__ kvh4,
    const int* __restrict__ offsets, const int* __restrict__ csr_src,
    const float* __restrict__ g, const float* __restrict__ b,
    int N, float* __restrict__ H2) {
  int wid = threadIdx.x >> 6, lane = threadIdx.x & 63;
  int n = blockIdx.x * 4 + wid;
  if (n >= N) return;
  int sub = lane & 15;
  uint2 qw = *(const uint2*)&qh[(size_t)n * 64 + sub * 4];
  uint2 rw = *(const uint2*)&H1h[(size_t)n * 64 + sub * 4];  // fp16 residual
  const __half2* rp = (const __half2*)&rw;
  float2 ra = __half22float2(rp[0]), rb2 = __half22float2(rp[1]);
  float4 r4 = make_float4(ra.x, ra.y, rb2.x, rb2.y);
  int e0 = offsets[n];
  int deg = offsets[n + 1] - e0;
  float denom = 0.f;
  float4 acc = make_float4(0.f, 0.f, 0.f, 0.f);
  edge_loop_h(kvh4, csr_src, e0, deg, lane, qw, denom, acc);
  float inv = 1.0f / (denom + 1e-16f);
  float4 out4 = make_float4(acc.x * inv, acc.y * inv, acc.z * inv, acc.w * inv);
  float4 o = ln_compute(out4, r4, g, b, lane);
  if (lane < 16) *(float4*)&H2[(size_t)n * 64 + lane * 4] = o;
}

// ---- Pooling: B x CHUNKS blocks, LDS reduce, 1 atomic/channel/block -----

#define POOL_CHUNKS 16

__global__ void __launch_bounds__(256) k_pool(const float* __restrict__ H2,
                                              const int* __restrict__ ptr,
                                              float* __restrict__ Q) {
  __shared__ float sh[4 * 64];
  int gI = blockIdx.x / POOL_CHUNKS;
  int c  = blockIdx.x % POOL_CHUNKS;
  int start = ptr[gI], end = ptr[gI + 1];
  int cnt = end - start;
  int per = (cnt + POOL_CHUNKS - 1) / POOL_CHUNKS;
  int s = start + c * per;
  int e = min(s + per, end);
  int wid = threadIdx.x >> 6, lane = threadIdx.x & 63;
  float acc = 0.f;
  for (int n = s + wid; n < e; n += 4) acc += H2[(size_t)n * 64 + lane];
  sh[wid * 64 + lane] = acc;
  __syncthreads();
  if (wid == 0) {
    float v = sh[lane] + sh[64 + lane] + sh[128 + lane] + sh[192 + lane];
    atomicAdd(&Q[(size_t)gI * 64 + lane], v / (float)cnt);
  }
}

// ---- Launch -------------------------------------------------------------

extern "C" void kernel_launch(void* const* d_in, const int* in_sizes, int n_in,
                              void* d_out, int out_size, void* d_ws, size_t ws_size,
                              hipStream_t stream) {
  const float* nodes = (const float*)d_in[0];
  const int* eidx    = (const int*)d_in[1];
  const int* bptr    = (const int*)d_in[2];
  const float* Wq1 = (const float*)d_in[3];
  const float* Wk1 = (const float*)d_in[4];
  const float* Wv1 = (const float*)d_in[5];
  const float* Wr1 = (const float*)d_in[6];
  const float* g1  = (const float*)d_in[7];
  const float* b1  = (const float*)d_in[8];
  const float* Wq2 = (const float*)d_in[9];
  const float* Wk2 = (const float*)d_in[10];
  const float* Wv2 = (const float*)d_in[11];
  const float* g2  = (const float*)d_in[12];
  const float* b2  = (const float*)d_in[13];

  const int N = in_sizes[0] / 13;
  const int E = in_sizes[1] / 2;
  const int B = in_sizes[2] - 1;
  const int* srcA = eidx;
  const int* dstA = eidx + E;

  char* w = (char*)d_ws;
  int* counts    = (int*)w; w += (size_t)N * 4;          // reused as scatter cursor
  int* offsets   = (int*)w; w += (size_t)(N + 1) * 4;
  int* blockSums = (int*)w; w += 256 * 4;
  int* csr_src   = (int*)w; w += (size_t)E * 4;
  w = (char*)(((uintptr_t)w + 255) & ~(uintptr_t)255);
  __half* kvh = (__half*)w; w += (size_t)N * 128 * 2;  // fp16 [k0..3|v0..3] chunks
  __half* qh  = (__half*)w; w += (size_t)N * 64 * 2;   // fp16 q, pre-scaled
  float*  rb  = (float*)w;  w += (size_t)N * 64 * 4;   // fp32 residual (layer 1)
  __half* H1h = (__half*)rb;  // rb dead after gat1 -> fp16 H1 (proj2m A + gat2 res)

  float* H2 = (float*)d_out;
  float* Q  = H2 + (size_t)N * 64;

  const int NB = (N + 255) / 256;
  const int EB = (E + 255) / 256;
  const int GB = (N + 3) / 4;
  const int NREG = ((N - 1) >> 13) + 1;  // 8192-node regions

  k_zero<<<256, 256, 0, stream>>>(counts, N, Q, B * 64);
  k_count<<<EB * 8, 256, 0, stream>>>(dstA, E, NREG, counts);
  k_scan1<<<NB, 256, 0, stream>>>(counts, N, offsets, blockSums);
  k_scan3<<<NB, 256, 0, stream>>>(offsets, counts, blockSums, N, E, NB);
  k_scatter<<<EB * 8, 256, 0, stream>>>(srcA, dstA, E, NREG, counts, csr_src);

  k_proj1<<<(N * 64 + 255) / 256, 256, 0, stream>>>(nodes, Wk1, Wv1, Wq1, Wr1, N,
                                                    kvh, qh, rb);
  k_gat1<<<GB, 256, 0, stream>>>(qh, rb, (const uint4*)kvh, offsets, csr_src,
                                 g1, b1, N, H1h);
  k_proj2m<<<392, 256, 0, stream>>>(H1h, Wk2, Wv2, Wq2, N, kvh, qh);
  k_gat2<<<GB, 256, 0, stream>>>(H1h, qh, (const uint4*)kvh, offsets, csr_src,
                                 g2, b2, N, H2);
  k_pool<<<B * POOL_CHUNKS, 256, 0, stream>>>(H2, bptr, Q);
}